// Round 6
// baseline (73.790 us; speedup 1.0000x reference)
//
#include <hip/hip_runtime.h>

// GridMatch: A=8, B=8, N=2048, grid 640x480 per (a,b) image.
// Per-image LDS hash: no global grids, no clear passes, 2 launches total.
#define AD 8
#define BD 8
#define NP 2048
#define MPTS (AD*BD*NP)            // 131072 points
#define NIMG (AD*BD)               // 64 images
#define HSZ 4096                   // LDS hash slots (>= max distinct cells/image)
#define RCAP 2048                  // max matches/image (<= min(#src cells, #dst cells))

// Match records, grouped by image. Fully rewritten every call (no invariants).
__device__ int g_cnt[NIMG];
__device__ int g_rc[NIMG*RCAP];    // local cell index (x*gh + y) — row-major rank key
__device__ int g_rs[NIMG*RCAP];    // global src point id
__device__ int g_rd[NIMG*RCAP];    // global dst point id

// ---- k1: 256 blocks. All blocks pad their 512-row output slice (rows < n get
// overwritten by k_emit). Blocks 0..63 additionally hash their image in LDS:
// insert src/dst (atomicMax id+1 per cell), then scan table for cells with both.
__global__ __launch_bounds__(256) void k_hash(
    const float* __restrict__ ps, const float* __restrict__ pd,
    float* __restrict__ out,
    const int* __restrict__ ph, const int* __restrict__ pw,
    const int* __restrict__ pg) {
  __shared__ int hkey[HSZ];
  __shared__ int hsrc[HSZ];
  __shared__ int hdst[HSZ];
  __shared__ int lcnt;

  int b = blockIdx.x, tid = threadIdx.x;

  // ---- padding fill (coalesced float4): rows [b*512, b*512+512) ----
  {
    float4 z  = make_float4(0.f, 0.f, 0.f, 0.f);
    float4 m1 = make_float4(-1.f, -1.f, -1.f, -1.f);
    ((float4*)out)[b*256 + tid]              = z;   // src_coord_m
    ((float4*)(out + 2*MPTS))[b*256 + tid]   = z;   // dst_coord_m
    ((float4*)(out + 4*MPTS))[b*256 + tid]   = m1;  // src_bn
    ((float4*)(out + 6*MPTS))[b*256 + tid]   = m1;  // dst_an
    if (tid < 128)
      ((float4*)(out + 8*MPTS))[b*128 + tid] = z;   // valid
  }

  if (b >= NIMG) return;   // pad-only blocks

  for (int i = tid; i < HSZ; i += 256) { hkey[i] = -1; hsrc[i] = 0; hdst[i] = 0; }
  if (tid == 0) lcnt = 0;
  __syncthreads();

  int h = *ph, w = *pw, gs = *pg;
  int gh = h * gs, gw = w * gs;
  float sx = (float)((gw - 1) * 0.5);
  float sy = (float)((gh - 1) * 0.5);

  // insert: claim slot for cell c (linear probe), atomicMax the side's id field
  auto insert = [&](float px, float py, int gid, int* field) {
    if (!(px >= -1.f && px <= 1.f && py >= -1.f && py <= 1.f)) return;
    int c = (int)((px + 1.f) * sx) * gh + (int)((py + 1.f) * sy);  // local row-major
    int i = (int)(((unsigned)c * 2654435761u) >> 20) & (HSZ - 1);
    while (true) {
      int k = atomicCAS(&hkey[i], -1, c);
      if (k == -1 || k == c) { atomicMax(&field[i], gid + 1); return; }
      i = (i + 1) & (HSZ - 1);
    }
  };

  const float4* sp = (const float4*)ps + b * (NP/2);   // this image's points
  const float4* dp = (const float4*)pd + b * (NP/2);
  int gbase = b * NP;

#pragma unroll
  for (int k = 0; k < NP/512; ++k) {                   // 4 x 256 float4 = 2048 pts
    int f = k*256 + tid;                               // float4 idx -> pts 2f, 2f+1
    float4 s2 = sp[f];
    insert(s2.x, s2.y, gbase + 2*f,     hsrc);
    insert(s2.z, s2.w, gbase + 2*f + 1, hsrc);
    float4 d2 = dp[f];
    insert(d2.x, d2.y, gbase + 2*f,     hdst);
    insert(d2.z, d2.w, gbase + 2*f + 1, hdst);
  }
  __syncthreads();

  // scan table: cells holding both a src and a dst winner -> match record
  for (int i = tid; i < HSZ; i += 256) {
    if (hkey[i] >= 0) {
      int s = hsrc[i], d = hdst[i];
      if (s > 0 && d > 0) {
        int slot = atomicAdd(&lcnt, 1);
        g_rc[b*RCAP + slot] = hkey[i];
        g_rs[b*RCAP + slot] = s - 1;
        g_rd[b*RCAP + slot] = d - 1;
      }
    }
  }
  __syncthreads();
  if (tid == 0) g_cnt[b] = lcnt;
}

// ---- k2: single block. Prefix-sum the 64 counts; rank each record within its
// image by cell comparison (cells unique); write matched rows at global ranks.
__global__ __launch_bounds__(256) void k_emit(
    const float* __restrict__ ps, const float* __restrict__ pd,
    float* __restrict__ out,
    const int* __restrict__ ph, const int* __restrict__ pw,
    const int* __restrict__ pg) {
  __shared__ int scnt[NIMG];
  __shared__ int soff[NIMG];
  int tid = threadIdx.x;
  if (tid < NIMG) scnt[tid] = g_cnt[tid];
  __syncthreads();
  if (tid == 0) {
    int acc = 0;
    for (int i = 0; i < NIMG; ++i) { soff[i] = acc; acc += scnt[i]; }
  }
  __syncthreads();

  int h = *ph, w = *pw, gs = *pg;
  int gh = h * gs, gw = w * gs;
  float sx = (float)((gw - 1) * 0.5);
  float sy = (float)((gh - 1) * 0.5);
  float fx = (float)((double)(h - 1) / (double)(gh - 1));  // pairs with x (faithful)
  float fy = (float)((double)(w - 1) / (double)(gw - 1));

  float* out0 = out;               // src_coord_m [M,2]
  float* out1 = out + 2*MPTS;      // dst_coord_m [M,2]
  float* out2 = out + 4*MPTS;      // src_bn      [M,2]
  float* out3 = out + 6*MPTS;      // dst_an      [M,2]
  float* out4 = out + 8*MPTS;      // valid       [M]

  for (int ab = 0; ab < NIMG; ++ab) {
    int cnt = scnt[ab];
    for (int j = tid; j < cnt; j += 256) {
      int ci = g_rc[ab*RCAP + j];
      int rank = soff[ab];
      for (int i = 0; i < cnt; ++i) rank += (int)(g_rc[ab*RCAP + i] < ci);
      int s = g_rs[ab*RCAP + j], d = g_rd[ab*RCAP + j];
      float2 a2 = ((const float2*)ps)[s];
      out0[2*rank]   = (a2.x + 1.f) * sx * fx;
      out0[2*rank+1] = (a2.y + 1.f) * sy * fy;
      float2 b2 = ((const float2*)pd)[d];
      out1[2*rank]   = (b2.x + 1.f) * sx * fx;
      out1[2*rank+1] = (b2.y + 1.f) * sy * fy;
      out2[2*rank]   = (float)((s / NP) % BD);
      out2[2*rank+1] = (float)(s % NP);
      out3[2*rank]   = (float)(d / (BD * NP));
      out3[2*rank+1] = (float)(d % NP);
      out4[rank]     = 1.f;
    }
  }
}

extern "C" void kernel_launch(void* const* d_in, const int* in_sizes, int n_in,
                              void* d_out, int out_size, void* d_ws, size_t ws_size,
                              hipStream_t stream) {
  const float* ps = (const float*)d_in[0];
  const float* pd = (const float*)d_in[1];
  const int* ph = (const int*)d_in[2];
  const int* pw = (const int*)d_in[3];
  const int* pg = (const int*)d_in[4];
  float* out = (float*)d_out;

  k_hash<<<MPTS/512, 256, 0, stream>>>(ps, pd, out, ph, pw, pg);  // 256 blocks
  k_emit<<<1,        256, 0, stream>>>(ps, pd, out, ph, pw, pg);
}

// Round 7
// 20.571 us; speedup vs baseline: 3.5871x; 3.5871x over previous
//
#include <hip/hip_runtime.h>

// GridMatch: A=8, B=8, N=2048, grid 640x480 per (a,b) image.
// Per-image LDS hash: no global grids, no clear passes, 2 launches total.
#define AD 8
#define BD 8
#define NP 2048
#define MPTS (AD*BD*NP)            // 131072 points
#define NIMG (AD*BD)               // 64 images
#define HSZ 4096                   // LDS hash slots (>= max distinct cells/image)
#define RCAP 2048                  // max matches/image (<= min(#src cells, #dst cells))

// Match records, grouped by image. Fully rewritten every call (no invariants).
__device__ int g_cnt[NIMG];
__device__ int g_rc[NIMG*RCAP];    // local cell index (x*gh + y) — row-major rank key
__device__ int g_rs[NIMG*RCAP];    // global src point id
__device__ int g_rd[NIMG*RCAP];    // global dst point id

// ---- k1: 256 blocks. All blocks pad their 512-row output slice (rows < n get
// overwritten by k_emit). Blocks 0..63 additionally hash their image in LDS:
// insert src/dst (atomicMax id+1 per cell), then scan table for cells with both.
__global__ __launch_bounds__(256) void k_hash(
    const float* __restrict__ ps, const float* __restrict__ pd,
    float* __restrict__ out,
    const int* __restrict__ ph, const int* __restrict__ pw,
    const int* __restrict__ pg) {
  __shared__ int hkey[HSZ];
  __shared__ int hsrc[HSZ];
  __shared__ int hdst[HSZ];
  __shared__ int lcnt;

  int b = blockIdx.x, tid = threadIdx.x;

  // ---- padding fill (coalesced float4): rows [b*512, b*512+512) ----
  {
    float4 z  = make_float4(0.f, 0.f, 0.f, 0.f);
    float4 m1 = make_float4(-1.f, -1.f, -1.f, -1.f);
    ((float4*)out)[b*256 + tid]              = z;   // src_coord_m
    ((float4*)(out + 2*MPTS))[b*256 + tid]   = z;   // dst_coord_m
    ((float4*)(out + 4*MPTS))[b*256 + tid]   = m1;  // src_bn
    ((float4*)(out + 6*MPTS))[b*256 + tid]   = m1;  // dst_an
    if (tid < 128)
      ((float4*)(out + 8*MPTS))[b*128 + tid] = z;   // valid
  }

  if (b >= NIMG) return;   // pad-only blocks

  for (int i = tid; i < HSZ; i += 256) { hkey[i] = -1; hsrc[i] = 0; hdst[i] = 0; }
  if (tid == 0) lcnt = 0;
  __syncthreads();

  int h = *ph, w = *pw, gs = *pg;
  int gh = h * gs, gw = w * gs;
  float sx = (float)((gw - 1) * 0.5);
  float sy = (float)((gh - 1) * 0.5);

  // insert: claim slot for cell c (linear probe), atomicMax the side's id field
  auto insert = [&](float px, float py, int gid, int* field) {
    if (!(px >= -1.f && px <= 1.f && py >= -1.f && py <= 1.f)) return;
    int c = (int)((px + 1.f) * sx) * gh + (int)((py + 1.f) * sy);  // local row-major
    int i = (int)(((unsigned)c * 2654435761u) >> 20) & (HSZ - 1);
    while (true) {
      int k = atomicCAS(&hkey[i], -1, c);
      if (k == -1 || k == c) { atomicMax(&field[i], gid + 1); return; }
      i = (i + 1) & (HSZ - 1);
    }
  };

  const float4* sp = (const float4*)ps + b * (NP/2);   // this image's points
  const float4* dp = (const float4*)pd + b * (NP/2);
  int gbase = b * NP;

#pragma unroll
  for (int k = 0; k < NP/512; ++k) {                   // 4 x 256 float4 = 2048 pts
    int f = k*256 + tid;                               // float4 idx -> pts 2f, 2f+1
    float4 s2 = sp[f];
    insert(s2.x, s2.y, gbase + 2*f,     hsrc);
    insert(s2.z, s2.w, gbase + 2*f + 1, hsrc);
    float4 d2 = dp[f];
    insert(d2.x, d2.y, gbase + 2*f,     hdst);
    insert(d2.z, d2.w, gbase + 2*f + 1, hdst);
  }
  __syncthreads();

  // scan table: cells holding both a src and a dst winner -> match record
  for (int i = tid; i < HSZ; i += 256) {
    if (hkey[i] >= 0) {
      int s = hsrc[i], d = hdst[i];
      if (s > 0 && d > 0) {
        int slot = atomicAdd(&lcnt, 1);
        g_rc[b*RCAP + slot] = hkey[i];
        g_rs[b*RCAP + slot] = s - 1;
        g_rd[b*RCAP + slot] = d - 1;
      }
    }
  }
  __syncthreads();
  if (tid == 0) g_cnt[b] = lcnt;
}

// ---- k2: 64 blocks, one per image. Each block computes its image's global
// offset from the 64 counts, ranks its records by cell (unique), writes rows.
__global__ __launch_bounds__(256) void k_emit(
    const float* __restrict__ ps, const float* __restrict__ pd,
    float* __restrict__ out,
    const int* __restrict__ ph, const int* __restrict__ pw,
    const int* __restrict__ pg) {
  __shared__ int scnt[NIMG];
  __shared__ int soff;
  int tid = threadIdx.x, ab = blockIdx.x;
  if (tid < NIMG) scnt[tid] = g_cnt[tid];
  __syncthreads();
  if (tid == 0) {
    int acc = 0;
    for (int i = 0; i < ab; ++i) acc += scnt[i];
    soff = acc;
  }
  __syncthreads();

  int cnt = scnt[ab];
  if (tid >= cnt) return;   // cnt << 256 in practice; strided loop unneeded but kept safe
  int h = *ph, w = *pw, gs = *pg;
  int gh = h * gs, gw = w * gs;
  float sx = (float)((gw - 1) * 0.5);
  float sy = (float)((gh - 1) * 0.5);
  float fx = (float)((double)(h - 1) / (double)(gh - 1));  // pairs with x (faithful)
  float fy = (float)((double)(w - 1) / (double)(gw - 1));

  float* out0 = out;               // src_coord_m [M,2]
  float* out1 = out + 2*MPTS;      // dst_coord_m [M,2]
  float* out2 = out + 4*MPTS;      // src_bn      [M,2]
  float* out3 = out + 6*MPTS;      // dst_an      [M,2]
  float* out4 = out + 8*MPTS;      // valid       [M]

  for (int j = tid; j < cnt; j += 256) {
    int ci = g_rc[ab*RCAP + j];
    int rank = soff;
    for (int i = 0; i < cnt; ++i) rank += (int)(g_rc[ab*RCAP + i] < ci);  // cells unique
    int s = g_rs[ab*RCAP + j], d = g_rd[ab*RCAP + j];
    float2 a2 = ((const float2*)ps)[s];
    out0[2*rank]   = (a2.x + 1.f) * sx * fx;
    out0[2*rank+1] = (a2.y + 1.f) * sy * fy;
    float2 b2 = ((const float2*)pd)[d];
    out1[2*rank]   = (b2.x + 1.f) * sx * fx;
    out1[2*rank+1] = (b2.y + 1.f) * sy * fy;
    out2[2*rank]   = (float)((s / NP) % BD);
    out2[2*rank+1] = (float)(s % NP);
    out3[2*rank]   = (float)(d / (BD * NP));
    out3[2*rank+1] = (float)(d % NP);
    out4[rank]     = 1.f;
  }
}

extern "C" void kernel_launch(void* const* d_in, const int* in_sizes, int n_in,
                              void* d_out, int out_size, void* d_ws, size_t ws_size,
                              hipStream_t stream) {
  const float* ps = (const float*)d_in[0];
  const float* pd = (const float*)d_in[1];
  const int* ph = (const int*)d_in[2];
  const int* pw = (const int*)d_in[3];
  const int* pg = (const int*)d_in[4];
  float* out = (float*)d_out;

  k_hash<<<MPTS/512, 256, 0, stream>>>(ps, pd, out, ph, pw, pg);  // 256 blocks
  k_emit<<<NIMG,     256, 0, stream>>>(ps, pd, out, ph, pw, pg);  // 64 blocks
}